// Round 4
// baseline (263.757 us; speedup 1.0000x reference)
//
#include <hip/hip_runtime.h>
#include <hip/hip_bf16.h>

// Problem constants
#define N_NODES 4096
#define BATCH   128
#define DD      32           // D_IN == D_OUT

typedef float  f32x4  __attribute__((ext_vector_type(4)));
typedef __bf16 bf16x8 __attribute__((ext_vector_type(8)));
typedef int    i32x4  __attribute__((ext_vector_type(4)));
typedef int    i32x8  __attribute__((ext_vector_type(8)));

#define PREP_BLOCKS 2048
#define TR_BLOCKS   4096   // 64x64 tiles

// async global->LDS, 16 B per lane. LDS dest must be linear in lane (uniform base + lane*16).
__device__ __forceinline__ void async_copy16(const void* g, void* l) {
    __builtin_amdgcn_global_load_lds(
        (const __attribute__((address_space(1))) unsigned int*)g,
        (__attribute__((address_space(3))) unsigned int*)l,
        16, 0, 0);
}

// pack 4 floats -> 4 fp8 e4m3 bytes (OCP), one dword
__device__ __forceinline__ unsigned pack_fp8x4(float a, float b, float c, float d) {
    int v = __builtin_amdgcn_cvt_pk_fp8_f32(a, b, 0, false);   // bytes 0,1
    v     = __builtin_amdgcn_cvt_pk_fp8_f32(c, d, v, true);    // bytes 2,3
    return (unsigned)v;
}

// ---------------------------------------------------------------------------
// Pre-stage (unchanged, known-good):
// Blocks [0, PREP_BLOCKS): T8[m=(b*32+q)][i] = fp8( x @ Wn )
// Blocks [PREP_BLOCKS, +TR_BLOCKS): adjT8[j][i] = fp8( adj[i][j] * 4096 )
//   (2^12 scale removed exactly by the GEMM's B e8m0 scale byte 0x73)
// ---------------------------------------------------------------------------
__global__ __launch_bounds__(256) void k_pre(
    const float* __restrict__ x, const float* __restrict__ adj,
    const float* __restrict__ Wn,
    unsigned char* __restrict__ T8, unsigned char* __restrict__ adjT8)
{
    __shared__ float ts[64][65];
    const int tid = threadIdx.x;

    if (blockIdx.x < PREP_BLOCKS) {
        // ---- prep branch (MFMA, no LDS) ----
        const int lane = tid & 63;
        const int gw   = (blockIdx.x * 256 + tid) >> 6;  // wave id 0..8191
        const int m    = lane & 15;   // A row / C col index
        const int quad = lane >> 4;   // k-quad

        bf16x8 bn[2];
#pragma unroll
        for (int h = 0; h < 2; ++h) {
            const int n = m + h * 16;
#pragma unroll
            for (int j = 0; j < 8; ++j) {
                const int k = quad * 8 + j;
                bn[h][j] = (__bf16)Wn[k * 32 + n];
            }
        }

        for (int t = gw; t < 32768; t += 8192) {       // 16-row tiles, 4 iters/wave
            const int row0 = t << 4;                   // global row = b*4096 + i0
            const int b    = row0 >> 12;
            const int i0   = row0 & 4095;

            const float4* xp = (const float4*)(x + (size_t)(row0 + m) * DD + quad * 8);
            const float4 x0 = xp[0], x1 = xp[1];
            bf16x8 a;
            a[0] = (__bf16)x0.x; a[1] = (__bf16)x0.y; a[2] = (__bf16)x0.z; a[3] = (__bf16)x0.w;
            a[4] = (__bf16)x1.x; a[5] = (__bf16)x1.y; a[6] = (__bf16)x1.z; a[7] = (__bf16)x1.w;

            const f32x4 z = {};
            const f32x4 cT0 = __builtin_amdgcn_mfma_f32_16x16x32_bf16(a, bn[0], z, 0, 0, 0);
            const f32x4 cT1 = __builtin_amdgcn_mfma_f32_16x16x32_bf16(a, bn[1], z, 0, 0, 0);

            // C/D: col=lane&15, row=quad*4+reg (i-local, 4 consecutive)
            *(unsigned*)&T8[((size_t)(b * 32 + m))      * N_NODES + i0 + quad * 4] =
                pack_fp8x4(cT0[0], cT0[1], cT0[2], cT0[3]);
            *(unsigned*)&T8[((size_t)(b * 32 + m + 16)) * N_NODES + i0 + quad * 4] =
                pack_fp8x4(cT1[0], cT1[1], cT1[2], cT1[3]);
        }
    } else {
        // ---- transpose branch ----
        const int bid = blockIdx.x - PREP_BLOCKS;
        const int cx  = tid & 63;
        const int cy  = tid >> 6;
        const int i0  = (bid >> 6) << 6;
        const int j0  = (bid & 63) << 6;
#pragma unroll
        for (int r = 0; r < 16; ++r) {
            const int row = cy * 16 + r;
            ts[row][cx] = adj[(size_t)(i0 + row) * N_NODES + j0 + cx];
        }
        __syncthreads();
        const int il = (tid & 7) * 8;
        const int jb = tid >> 3;          // 0..31
#pragma unroll
        for (int rr = 0; rr < 2; ++rr) {
            const int jl = jb + rr * 32;
            float v[8];
#pragma unroll
            for (int k = 0; k < 8; ++k) v[k] = ts[il + k][jl] * 4096.0f;
            uint2 p;
            p.x = pack_fp8x4(v[0], v[1], v[2], v[3]);
            p.y = pack_fp8x4(v[4], v[5], v[6], v[7]);
            *(uint2*)&adjT8[(size_t)(j0 + jl) * N_NODES + i0 + il] = p;
        }
    }
}

// ---------------------------------------------------------------------------
// GEMM v4b (v4 + sched_barrier hardening): 256x256 block tile, BK=128B,
// 512 thr / 8 waves (2M x 4N, wave tile 128x64), double-buffered XOR-swizzled
// LDS (2 x 64 KB), 4 phases per K-tile of 8 MFMA each with s_setprio, counted
// vmcnt(6) once per tile (never 0 in the main loop). Staging schedule
// (tile t, buf c = t&1):
//   ph0: issue A rounds 1,3 of tile t+1 -> buf o      (2 loads/thr)
//   ph1: issue B rounds 0-3 of tile t+2 -> buf c      (4)  [B dead: reg-held]
//   ph2: issue A rounds 0,2 of tile t+2 -> buf c      (2)  [rows read ph0-1]
//   ph3: vmcnt(6) + barrier  (clears exactly tile t+1's 8 loads, FIFO-verified)
// Round r = 64 rows of 128 B. sched_barrier(0) after every s_barrier pins the
// next phase's ds_reads below the barrier (compiler-hoist hazard, rule 18).
//           out[b*131072 + j*32 + q] = relu(U + C),  m = b*32+q
// U (self part) fused in epilogue from x, bit-identical to v3.
// ---------------------------------------------------------------------------
__global__ __launch_bounds__(512, 2) void k_gemm_neigh(
    const unsigned char* __restrict__ A8,   // T8    [4096][4096] fp8
    const unsigned char* __restrict__ B8,   // adjT8 [4096][4096] fp8 (x4096)
    const float* __restrict__ x,            // [128][4096][32] f32
    const float* __restrict__ Ws,           // [32][32] f32
    float* __restrict__ out)                // [128][4096][32] pure store
{
    __shared__ alignas(16) unsigned char As[2 * 256 * 128];   // 64 KB
    __shared__ alignas(16) unsigned char Bs[2 * 256 * 128];   // 64 KB

    const int tid   = threadIdx.x;
    const int lane  = tid & 63;
    const int wid   = tid >> 6;
    const int lr    = lane & 15;   // row (A) / col (B) within 16-tile
    const int lq    = lane >> 4;   // k-chunk (32 bytes)
    const int sw    = lr & 7;      // read-side XOR swizzle
    const int waveM = (wid >> 2) * 128;   // 2 M-waves
    const int waveN = (wid & 3) * 64;     // 4 N-waves

    // bijective XCD swizzle: 256 wgs, 8 XCDs, 32 contiguous wgs per XCD
    const int wg = (blockIdx.x & 7) * 32 + (blockIdx.x >> 3);
    const int Mb = (wg >> 4) << 8;
    const int Nb = (wg & 15) << 8;

    // staging: round r = rows [64r, 64r+64); thread covers row tid>>3, chunk
    // tid&7 pre-swizzled by row&7; LDS dest = base + r*8192 + tid*16 (linear).
    const int    srow  = tid >> 3;   // 0..63
    const int    scol  = ((tid & 7) ^ (srow & 7)) * 16;
    const size_t abase = (size_t)(Mb + srow) * 4096 + scol;
    const size_t bbase = (size_t)(Nb + srow) * 4096 + scol;

#define STA(bufi, r, t)                                                        \
    async_copy16(A8 + abase + (size_t)(r) * 64 * 4096 + (t) * 128,             \
                 (char*)As + (bufi) * 32768 + (r) * 8192 + tid * 16)
#define STB(bufi, r, t)                                                        \
    async_copy16(B8 + bbase + (size_t)(r) * 64 * 4096 + (t) * 128,             \
                 (char*)Bs + (bufi) * 32768 + (r) * 8192 + tid * 16)
#define BAR()                                                                  \
    {                                                                          \
        asm volatile("s_waitcnt lgkmcnt(0)" ::: "memory");                     \
        __builtin_amdgcn_s_barrier();                                          \
        __builtin_amdgcn_sched_barrier(0);                                     \
    }

    f32x4 acc[8][4] = {};

    const int c0 = ((2 * lq)     ^ sw) * 16;
    const int c1 = ((2 * lq + 1) ^ sw) * 16;

    // prologue: tile0 fully, then tile1's B0-3 + A0,2; wait the oldest 8.
#pragma unroll
    for (int r = 0; r < 4; ++r) STA(0, r, 0);
#pragma unroll
    for (int r = 0; r < 4; ++r) STB(0, r, 0);
#pragma unroll
    for (int r = 0; r < 4; ++r) STB(1, r, 1);
    STA(1, 0, 1); STA(1, 2, 1);
    asm volatile("s_waitcnt vmcnt(6)" ::: "memory");
    __builtin_amdgcn_s_barrier();
    __builtin_amdgcn_sched_barrier(0);

    for (int t = 0; t < 32; ++t) {
        const int c = t & 1, o = c ^ 1;
        const unsigned char* const cA = As + c * 32768;
        const unsigned char* const cB = Bs + c * 32768;

#define RD8(dst, base, row)                                                    \
    {                                                                          \
        const i32x4 _lo = *(const i32x4*)&(base)[(row) * 128 + c0];            \
        const i32x4 _hi = *(const i32x4*)&(base)[(row) * 128 + c1];            \
        dst[0]=_lo[0]; dst[1]=_lo[1]; dst[2]=_lo[2]; dst[3]=_lo[3];            \
        dst[4]=_hi[0]; dst[5]=_hi[1]; dst[6]=_hi[2]; dst[7]=_hi[3];            \
    }

        // ---- phase 0: all B frags (reg-held) + A fm0,1; stage A1,3(t+1)
        i32x8 bf[4];
#pragma unroll
        for (int fn = 0; fn < 4; ++fn) RD8(bf[fn], cB, waveN + fn * 16 + lr);
        i32x8 a0, a1;
        RD8(a0, cA, waveM + 0 * 16 + lr);
        RD8(a1, cA, waveM + 1 * 16 + lr);
        if (t + 1 < 32) { STA(o, 1, t + 1); STA(o, 3, t + 1); }
        __builtin_amdgcn_s_setprio(1);
#pragma unroll
        for (int fn = 0; fn < 4; ++fn)
            acc[0][fn] = __builtin_amdgcn_mfma_scale_f32_16x16x128_f8f6f4(
                a0, bf[fn], acc[0][fn], 0, 0, 0, 0x7F, 0, 0x73);
#pragma unroll
        for (int fn = 0; fn < 4; ++fn)
            acc[1][fn] = __builtin_amdgcn_mfma_scale_f32_16x16x128_f8f6f4(
                a1, bf[fn], acc[1][fn], 0, 0, 0, 0x7F, 0, 0x73);
        __builtin_amdgcn_s_setprio(0);
        BAR();

        // ---- phase 1: A fm2,3; stage B0-3(t+2) into buf c (B region dead)
        RD8(a0, cA, waveM + 2 * 16 + lr);
        RD8(a1, cA, waveM + 3 * 16 + lr);
        if (t + 2 < 32) { STB(c, 0, t + 2); STB(c, 1, t + 2);
                          STB(c, 2, t + 2); STB(c, 3, t + 2); }
        __builtin_amdgcn_s_setprio(1);
#pragma unroll
        for (int fn = 0; fn < 4; ++fn)
            acc[2][fn] = __builtin_amdgcn_mfma_scale_f32_16x16x128_f8f6f4(
                a0, bf[fn], acc[2][fn], 0, 0, 0, 0x7F, 0, 0x73);
#pragma unroll
        for (int fn = 0; fn < 4; ++fn)
            acc[3][fn] = __builtin_amdgcn_mfma_scale_f32_16x16x128_f8f6f4(
                a1, bf[fn], acc[3][fn], 0, 0, 0, 0x7F, 0, 0x73);
        __builtin_amdgcn_s_setprio(0);
        BAR();

        // ---- phase 2: A fm4,5; stage A0,2(t+2) (rows 0-63/128-191 dead)
        RD8(a0, cA, waveM + 4 * 16 + lr);
        RD8(a1, cA, waveM + 5 * 16 + lr);
        if (t + 2 < 32) { STA(c, 0, t + 2); STA(c, 2, t + 2); }
        __builtin_amdgcn_s_setprio(1);
#pragma unroll
        for (int fn = 0; fn < 4; ++fn)
            acc[4][fn] = __builtin_amdgcn_mfma_scale_f32_16x16x128_f8f6f4(
                a0, bf[fn], acc[4][fn], 0, 0, 0, 0x7F, 0, 0x73);
#pragma unroll
        for (int fn = 0; fn < 4; ++fn)
            acc[5][fn] = __builtin_amdgcn_mfma_scale_f32_16x16x128_f8f6f4(
                a1, bf[fn], acc[5][fn], 0, 0, 0, 0x7F, 0, 0x73);
        __builtin_amdgcn_s_setprio(0);
        BAR();

        // ---- phase 3: A fm6,7; counted vmcnt + tile barrier
        RD8(a0, cA, waveM + 6 * 16 + lr);
        RD8(a1, cA, waveM + 7 * 16 + lr);
        __builtin_amdgcn_s_setprio(1);
#pragma unroll
        for (int fn = 0; fn < 4; ++fn)
            acc[6][fn] = __builtin_amdgcn_mfma_scale_f32_16x16x128_f8f6f4(
                a0, bf[fn], acc[6][fn], 0, 0, 0, 0x7F, 0, 0x73);
#pragma unroll
        for (int fn = 0; fn < 4; ++fn)
            acc[7][fn] = __builtin_amdgcn_mfma_scale_f32_16x16x128_f8f6f4(
                a1, bf[fn], acc[7][fn], 0, 0, 0, 0x7F, 0, 0x73);
        __builtin_amdgcn_s_setprio(0);
        asm volatile("s_waitcnt lgkmcnt(0)" ::: "memory");
        if (t + 2 < 32)      { asm volatile("s_waitcnt vmcnt(6)" ::: "memory"); }
        else if (t + 1 < 32) { asm volatile("s_waitcnt vmcnt(0)" ::: "memory"); }
        __builtin_amdgcn_sched_barrier(0);
        if (t + 1 < 32) {
            __builtin_amdgcn_s_barrier();
            __builtin_amdgcn_sched_barrier(0);
        }
    }
#undef RD8
#undef STA
#undef STB
#undef BAR

    // ---- epilogue: U = bf16(x) @ bf16(Ws) in the same fragment layout as
    // acc (row=q=hh*16+lq*4+reg, col=j=lr), then relu(acc+U) pure store.
    const f32x4 z = {};
    bf16x8 ws[2];
#pragma unroll
    for (int h = 0; h < 2; ++h)
#pragma unroll
        for (int j = 0; j < 8; ++j)
            ws[h][j] = (__bf16)Ws[(lq * 8 + j) * 32 + lr + h * 16];

    const int b0 = (Mb + waveM) >> 5;    // wave's m-range = 128 rows = 4 batches
#pragma unroll
    for (int bb = 0; bb < 4; ++bb) {
        const int b = b0 + bb;
        bf16x8 xa[4];
#pragma unroll
        for (int fn = 0; fn < 4; ++fn) {
            const int gj = Nb + waveN + fn * 16 + lr;
            const float4* xp = (const float4*)(x + ((size_t)b * N_NODES + gj) * DD + lq * 8);
            const float4 x0 = xp[0], x1 = xp[1];
            xa[fn][0] = (__bf16)x0.x; xa[fn][1] = (__bf16)x0.y;
            xa[fn][2] = (__bf16)x0.z; xa[fn][3] = (__bf16)x0.w;
            xa[fn][4] = (__bf16)x1.x; xa[fn][5] = (__bf16)x1.y;
            xa[fn][6] = (__bf16)x1.z; xa[fn][7] = (__bf16)x1.w;
        }
#pragma unroll
        for (int hh = 0; hh < 2; ++hh) {
            const int fm = bb * 2 + hh;
            const int q0 = hh * 16 + lq * 4;
#pragma unroll
            for (int fn = 0; fn < 4; ++fn) {
                const f32x4 u = __builtin_amdgcn_mfma_f32_16x16x32_bf16(
                    ws[hh], xa[fn], z, 0, 0, 0);
                const int gj = Nb + waveN + fn * 16 + lr;
                float* p = out + (size_t)b * (N_NODES * DD) + (size_t)gj * DD + q0;
                float4 v;
                v.x = fmaxf(acc[fm][fn][0] + u[0], 0.0f);
                v.y = fmaxf(acc[fm][fn][1] + u[1], 0.0f);
                v.z = fmaxf(acc[fm][fn][2] + u[2], 0.0f);
                v.w = fmaxf(acc[fm][fn][3] + u[3], 0.0f);
                *(float4*)p = v;
            }
        }
    }
}

extern "C" void kernel_launch(void* const* d_in, const int* in_sizes, int n_in,
                              void* d_out, int out_size, void* d_ws, size_t ws_size,
                              hipStream_t stream) {
    const float* x   = (const float*)d_in[0];  // [128, 4096*32]
    const float* adj = (const float*)d_in[1];  // [4096, 4096]
    const float* Wn  = (const float*)d_in[2];  // [32, 32]
    const float* Ws  = (const float*)d_in[3];  // [32, 32]
    float* out = (float*)d_out;                // [128, 4096*32]

    // workspace: T8 fp8 (16 MB) | adjT8 fp8 (16 MB)
    unsigned char* T8    = (unsigned char*)d_ws;
    unsigned char* adjT8 = T8 + (size_t)N_NODES * N_NODES;

    hipLaunchKernelGGL(k_pre, dim3(PREP_BLOCKS + TR_BLOCKS), dim3(256), 0, stream,
                       x, adj, Wn, T8, adjT8);
    hipLaunchKernelGGL(k_gemm_neigh, dim3(256), dim3(512), 0, stream,
                       T8, adjT8, x, Ws, out);
}